// Round 4
// baseline (115.885 us; speedup 1.0000x reference)
//
#include <hip/hip_runtime.h>
#include <math.h>

// Problem constants
#define BB 128
#define ND 32
#define NIJ 16384
#define EPS2 0.25f
#define EPS4 0.0625f

// Tiling
#define TIJ 32
#define NBLK (NIJ / TIJ)        // 512 blocks, 2/CU
#define NTHR 512

// LDS layout (floats). R1 [0,4352) holds cAB (phases 0-A), then w (phases B-C).
#define ROW_CAB 68              // [n][cA 32 | cB 32 | pad 4]
#define ROW_X   136             // [n][b 128 | pad 8]
#define ROW_W   136             // [ij][b 128 | pad 8]
#define ROW_KKV 68              // [ij][K 32 | KV 32 | pad 4]
#define X_OFF   4352
#define KKV_OFF 8704
#define CC_OFF  10880
#define LAM_OFF 10912
#define LDS_FL  10944           // 43776 B -> 2 blocks/CU

// Partial layout: part[blk][b][36]
#define PS 36
#define PART_PER_BLK (BB * PS)  // 4608

__global__ __launch_bounds__(NTHR, 4) void gmm_fused(
    const float* __restrict__ Xg,
    const float* __restrict__ tptr,
    const float* __restrict__ Mu0, const float* __restrict__ Mu1,
    const float* __restrict__ S0,  const float* __restrict__ S1,
    const float* __restrict__ Lam,
    float* __restrict__ part)
{
    __shared__ __align__(16) float lds[LDS_FL];
#define LD4(off) (*(const float4*)&lds[(off)])

    const int tid  = threadIdx.x;
    const int blk  = blockIdx.x;
    const int ij0g = blk * TIJ;
    const float t   = tptr[0];
    const float omt = 1.0f - t;

    // ---- Phase 0: coefficients + X staging ----
#pragma unroll
    for (int k = 0; k < (TIJ * ND) / NTHR; ++k) {
        const int idx = tid + k * NTHR;
        const int n   = idx & 31;
        const int ijl = idx >> 5;            // 0..31
        const int ij  = ij0g + ijl;
        const int i   = ij >> 7;
        const int j   = ij & 127;
        const float s0  = S0[i * ND + n];
        const float s1  = S1[j * ND + n];
        const float mu0 = Mu0[i * ND + n];
        const float mu1 = Mu1[j * ND + n];
        const float Ds  = sqrtf(4.0f * s0 * s1 + EPS4);
        const float Cs  = 0.5f * (Ds - EPS2);
        const float Sigma = omt * omt * s0 + t * t * s1
                          + 2.0f * t * omt * Cs + EPS2 * t * omt;
        const float St  = (t * s1 + omt * Cs) - (omt * s0 + t * Cs) - EPS2 * t;
        const float Mut = omt * mu0 + t * mu1;
        const float v   = mu1 - mu0;
        const float invS = 1.0f / Sigma;
        const float Kf  = St * invS;
        const float cA  = -0.5f * invS;
        const float cB  = Mut * invS;
        lds[n * ROW_CAB + ijl]      = cA;
        lds[n * ROW_CAB + 32 + ijl] = cB;
        lds[KKV_OFF + ijl * ROW_KKV + n]      = Kf;
        lds[KKV_OFF + ijl * ROW_KKV + 32 + n] = v - Kf * Mut;
        float cc = cA * Mut * Mut - 0.5f * __logf(Sigma);
        cc += __shfl_xor(cc, 1);
        cc += __shfl_xor(cc, 2);
        cc += __shfl_xor(cc, 4);
        cc += __shfl_xor(cc, 8);
        cc += __shfl_xor(cc, 16);
        if (n == 0) lds[CC_OFF + ijl] = cc;
    }
#pragma unroll
    for (int k = 0; k < (BB * ND) / NTHR; ++k) {
        const int idx = tid + k * NTHR;
        lds[X_OFF + (idx & 31) * ROW_X + (idx >> 5)] = Xg[idx];
    }
    if (tid < TIJ) lds[LAM_OFF + tid] = Lam[ij0g + tid];

    const int lane = tid & 63;
    const int wave = tid >> 6;
    const int bql  = (lane >> 2) & 3;
    const int b0   = (wave * 4 + bql) * 4;   // 0..124 step 4

    __syncthreads();

    // ---- Phase A: lw[4b][8ij], streaming n (nq = interleaved quarter) ----
    {
        const int ijg = lane & 3;
        const int nq  = lane >> 4;           // 0..3
        const int ijA = ijg * 8;
        float lw[32];
#pragma unroll
        for (int k = 0; k < 32; ++k) lw[k] = 0.0f;
#pragma unroll
        for (int tt = 0; tt < 8; ++tt) {
            const int n = tt * 4 + nq;
            const float4 A0 = LD4(n * ROW_CAB + ijA);
            const float4 A1 = LD4(n * ROW_CAB + ijA + 4);
            const float4 C0 = LD4(n * ROW_CAB + 32 + ijA);
            const float4 C1 = LD4(n * ROW_CAB + 32 + ijA + 4);
            const float4 XV = LD4(X_OFF + n * ROW_X + b0);
            const float4 XS = make_float4(XV.x * XV.x, XV.y * XV.y,
                                          XV.z * XV.z, XV.w * XV.w);
#define PA_ONE(bi, XSc, XVc) \
            lw[bi*8+0] = fmaf(C0.x, XVc, fmaf(A0.x, XSc, lw[bi*8+0])); \
            lw[bi*8+1] = fmaf(C0.y, XVc, fmaf(A0.y, XSc, lw[bi*8+1])); \
            lw[bi*8+2] = fmaf(C0.z, XVc, fmaf(A0.z, XSc, lw[bi*8+2])); \
            lw[bi*8+3] = fmaf(C0.w, XVc, fmaf(A0.w, XSc, lw[bi*8+3])); \
            lw[bi*8+4] = fmaf(C1.x, XVc, fmaf(A1.x, XSc, lw[bi*8+4])); \
            lw[bi*8+5] = fmaf(C1.y, XVc, fmaf(A1.y, XSc, lw[bi*8+5])); \
            lw[bi*8+6] = fmaf(C1.z, XVc, fmaf(A1.z, XSc, lw[bi*8+6])); \
            lw[bi*8+7] = fmaf(C1.w, XVc, fmaf(A1.w, XSc, lw[bi*8+7]));
            PA_ONE(0, XS.x, XV.x)
            PA_ONE(1, XS.y, XV.y)
            PA_ONE(2, XS.z, XV.z)
            PA_ONE(3, XS.w, XV.w)
#undef PA_ONE
        }
        // combine the 4 nq-quarters (lane bits 4,5)
#pragma unroll
        for (int k = 0; k < 32; ++k) {
            lw[k] += __shfl_xor(lw[k], 16);
            lw[k] += __shfl_xor(lw[k], 32);
        }

        __syncthreads();   // all phase-A reads of cAB done before w overwrites R1

        // ---- Phase B: w = exp(clip(lw + Cc)) * Lam; write w[ij][b] ----
        // lane handles bi = nq (b = b0 + nq)
        float lwb[8];
#pragma unroll
        for (int jj = 0; jj < 8; ++jj) {
            const float v0 = (nq & 2) ? lw[16 + jj] : lw[jj];
            const float v1 = (nq & 2) ? lw[24 + jj] : lw[8 + jj];
            lwb[jj] = (nq & 1) ? v1 : v0;
        }
#pragma unroll
        for (int jj = 0; jj < 8; ++jj) {
            const int ij = ijA + jj;
            float v = lwb[jj] + lds[CC_OFF + ij];
            v = fminf(fmaxf(v, -50.0f), 50.0f);
            lds[ij * ROW_W + b0 + nq] = __expf(v) * lds[LAM_OFF + ij];
        }
    }

    __syncthreads();

    // ---- Phase C: wk/wkv[4b][8n] accumulate over ij ----
    {
        const int ng  = lane & 3;
        const int n0  = ng * 8;
        const int ijq = lane >> 4;           // 0..3
        float wk[32], wkv[32], den4[4];
#pragma unroll
        for (int k = 0; k < 32; ++k) { wk[k] = 0.0f; wkv[k] = 0.0f; }
#pragma unroll
        for (int k = 0; k < 4; ++k) den4[k] = 0.0f;

#pragma unroll
        for (int tt = 0; tt < 8; ++tt) {
            const int ij = tt * 4 + ijq;     // 4 consecutive ij across ijq lanes
            const float4 WV = LD4(ij * ROW_W + b0);
            const float4 K0 = LD4(KKV_OFF + ij * ROW_KKV + n0);
            const float4 K1 = LD4(KKV_OFF + ij * ROW_KKV + n0 + 4);
            const float4 V0 = LD4(KKV_OFF + ij * ROW_KKV + 32 + n0);
            const float4 V1 = LD4(KKV_OFF + ij * ROW_KKV + 32 + n0 + 4);
#define PC_ONE(bi, WVc) \
            den4[bi] += WVc; \
            wk [bi*8+0] = fmaf(WVc, K0.x, wk [bi*8+0]); \
            wk [bi*8+1] = fmaf(WVc, K0.y, wk [bi*8+1]); \
            wk [bi*8+2] = fmaf(WVc, K0.z, wk [bi*8+2]); \
            wk [bi*8+3] = fmaf(WVc, K0.w, wk [bi*8+3]); \
            wk [bi*8+4] = fmaf(WVc, K1.x, wk [bi*8+4]); \
            wk [bi*8+5] = fmaf(WVc, K1.y, wk [bi*8+5]); \
            wk [bi*8+6] = fmaf(WVc, K1.z, wk [bi*8+6]); \
            wk [bi*8+7] = fmaf(WVc, K1.w, wk [bi*8+7]); \
            wkv[bi*8+0] = fmaf(WVc, V0.x, wkv[bi*8+0]); \
            wkv[bi*8+1] = fmaf(WVc, V0.y, wkv[bi*8+1]); \
            wkv[bi*8+2] = fmaf(WVc, V0.z, wkv[bi*8+2]); \
            wkv[bi*8+3] = fmaf(WVc, V0.w, wkv[bi*8+3]); \
            wkv[bi*8+4] = fmaf(WVc, V1.x, wkv[bi*8+4]); \
            wkv[bi*8+5] = fmaf(WVc, V1.y, wkv[bi*8+5]); \
            wkv[bi*8+6] = fmaf(WVc, V1.z, wkv[bi*8+6]); \
            wkv[bi*8+7] = fmaf(WVc, V1.w, wkv[bi*8+7]);
            PC_ONE(0, WV.x)
            PC_ONE(1, WV.y)
            PC_ONE(2, WV.z)
            PC_ONE(3, WV.w)
#undef PC_ONE
        }

        // combine over the 4 ijq groups (lane bits 4,5)
#pragma unroll
        for (int k = 0; k < 32; ++k) {
            wk[k]  += __shfl_xor(wk[k], 16);
            wk[k]  += __shfl_xor(wk[k], 32);
            wkv[k] += __shfl_xor(wkv[k], 16);
            wkv[k] += __shfl_xor(wkv[k], 32);
        }
#pragma unroll
        for (int k = 0; k < 4; ++k) {
            den4[k] += __shfl_xor(den4[k], 16);
            den4[k] += __shfl_xor(den4[k], 32);
        }

        // ---- Epilogue: num = X*wk + wkv, store block partials ----
        if (ijq == 0) {
            float num[32];
#pragma unroll
            for (int nj = 0; nj < 8; ++nj) {
                const float4 XQ = LD4(X_OFF + (n0 + nj) * ROW_X + b0);
                num[0 * 8 + nj] = fmaf(XQ.x, wk[0 * 8 + nj], wkv[0 * 8 + nj]);
                num[1 * 8 + nj] = fmaf(XQ.y, wk[1 * 8 + nj], wkv[1 * 8 + nj]);
                num[2 * 8 + nj] = fmaf(XQ.z, wk[2 * 8 + nj], wkv[2 * 8 + nj]);
                num[3 * 8 + nj] = fmaf(XQ.w, wk[3 * 8 + nj], wkv[3 * 8 + nj]);
            }
            float* dstb = part + blk * PART_PER_BLK;
#pragma unroll
            for (int bi = 0; bi < 4; ++bi) {
                float* dst = dstb + (b0 + bi) * PS + n0;
                *(float4*)dst =
                    make_float4(num[bi*8+0], num[bi*8+1], num[bi*8+2], num[bi*8+3]);
                *(float4*)(dst + 4) =
                    make_float4(num[bi*8+4], num[bi*8+5], num[bi*8+6], num[bi*8+7]);
            }
            if (ng == 0) {
#pragma unroll
                for (int bi = 0; bi < 4; ++bi)
                    dstb[(b0 + bi) * PS + 32] = den4[bi];
            }
        }
    }
#undef LD4
}

// One block per b: sum partials over the 512 blocks, divide, store out.
__global__ __launch_bounds__(256) void gmm_reduce(
    const float* __restrict__ part,
    float* __restrict__ out)
{
    const int b   = blockIdx.x;
    const int tid = threadIdx.x;            // 0..255
    const float* __restrict__ src0 = part + tid * PART_PER_BLK + b * PS;
    const float* __restrict__ src1 = src0 + 256 * PART_PER_BLK;

    float v[33];
#pragma unroll
    for (int c = 0; c < 8; ++c) {
        const float4 f0 = *(const float4*)(src0 + 4 * c);
        const float4 f1 = *(const float4*)(src1 + 4 * c);
        v[4*c+0] = f0.x + f1.x; v[4*c+1] = f0.y + f1.y;
        v[4*c+2] = f0.z + f1.z; v[4*c+3] = f0.w + f1.w;
    }
    v[32] = src0[32] + src1[32];

#pragma unroll
    for (int m = 1; m < 64; m <<= 1) {
#pragma unroll
        for (int k = 0; k < 33; ++k) v[k] += __shfl_xor(v[k], m);
    }

    __shared__ float red[4][33];
    const int w = tid >> 6;
    if ((tid & 63) == 0) {
#pragma unroll
        for (int k = 0; k < 33; ++k) red[w][k] = v[k];
    }
    __syncthreads();

    if (tid < ND) {
        const float num = red[0][tid] + red[1][tid] + red[2][tid] + red[3][tid];
        const float den = red[0][32] + red[1][32] + red[2][32] + red[3][32];
        out[b * ND + tid] = num / den;
    }
}

extern "C" void kernel_launch(void* const* d_in, const int* in_sizes, int n_in,
                              void* d_out, int out_size, void* d_ws, size_t ws_size,
                              hipStream_t stream)
{
    const float* X   = (const float*)d_in[0];
    const float* t   = (const float*)d_in[1];
    const float* Mu0 = (const float*)d_in[2];
    const float* Mu1 = (const float*)d_in[3];
    const float* S0  = (const float*)d_in[4];
    const float* S1  = (const float*)d_in[5];
    const float* Lam = (const float*)d_in[6];
    float* out  = (float*)d_out;
    float* part = (float*)d_ws;             // NBLK * PART_PER_BLK floats (~9.4 MB)

    gmm_fused<<<NBLK, NTHR, 0, stream>>>(X, t, Mu0, Mu1, S0, S1, Lam, part);
    gmm_reduce<<<BB, 256, 0, stream>>>(part, out);
}

// Round 5
// 110.138 us; speedup vs baseline: 1.0522x; 1.0522x over previous
//
#include <hip/hip_runtime.h>
#include <math.h>

// Problem constants
#define BB 128
#define ND 32
#define NIJ 16384
#define EPS2 0.25f
#define EPS4 0.0625f

// Tiling
#define TIJ 32
#define NBLK (NIJ / TIJ)        // 512 blocks
#define NTHR 512

// LDS layout (floats).
// Region0 [0,4352): cAB (phase 0-A), then w (phase B-C), then out-stage.
#define ROW_CAB 68              // [n][cA 32 | cB 32 | pad 4]
#define ROW_X   136             // [n][b 128 | pad 8]
#define ROW_W   136             // [ij][b 128 (swizzled) | pad 8]
#define ROW_KKV 68              // [ij][K 32 | KV 32 | pad 4]
#define X_OFF   4352
#define KKV_OFF 8704
#define CC_OFF  10880
#define LAM_OFF 10912
#define LDS_FL  10944           // 43776 B

// part layout per block: num[128][32] at 0, den[128] at 4096 -> 4224 floats
#define PART_STRIDE 4224
#define DEN_OFF 4096

__global__ __launch_bounds__(NTHR, 4) void gmm_fused(
    const float* __restrict__ Xg,
    const float* __restrict__ tptr,
    const float* __restrict__ Mu0, const float* __restrict__ Mu1,
    const float* __restrict__ S0,  const float* __restrict__ S1,
    const float* __restrict__ Lam,
    float* __restrict__ part)
{
    __shared__ __align__(16) float lds[LDS_FL];
#define LD4(off) (*(const float4*)&lds[(off)])

    const int tid  = threadIdx.x;
    const int blk  = blockIdx.x;
    const int ij0g = blk * TIJ;
    const float t   = tptr[0];
    const float omt = 1.0f - t;

    // ---- Phase 0: coefficients + X staging ----
#pragma unroll
    for (int k = 0; k < (TIJ * ND) / NTHR; ++k) {
        const int idx = tid + k * NTHR;
        const int n   = idx & 31;
        const int ijl = idx >> 5;            // 0..31
        const int ij  = ij0g + ijl;
        const int i   = ij >> 7;
        const int j   = ij & 127;
        const float s0  = S0[i * ND + n];
        const float s1  = S1[j * ND + n];
        const float mu0 = Mu0[i * ND + n];
        const float mu1 = Mu1[j * ND + n];
        const float Ds  = sqrtf(4.0f * s0 * s1 + EPS4);
        const float Cs  = 0.5f * (Ds - EPS2);
        const float Sigma = omt * omt * s0 + t * t * s1
                          + 2.0f * t * omt * Cs + EPS2 * t * omt;
        const float St  = (t * s1 + omt * Cs) - (omt * s0 + t * Cs) - EPS2 * t;
        const float Mut = omt * mu0 + t * mu1;
        const float v   = mu1 - mu0;
        const float invS = 1.0f / Sigma;
        const float Kf  = St * invS;
        const float cA  = -0.5f * invS;
        const float cB  = Mut * invS;
        lds[n * ROW_CAB + ijl]      = cA;
        lds[n * ROW_CAB + 32 + ijl] = cB;
        lds[KKV_OFF + ijl * ROW_KKV + n]      = Kf;
        lds[KKV_OFF + ijl * ROW_KKV + 32 + n] = v - Kf * Mut;
        float cc = cA * Mut * Mut - 0.5f * __logf(Sigma);
        cc += __shfl_xor(cc, 1);
        cc += __shfl_xor(cc, 2);
        cc += __shfl_xor(cc, 4);
        cc += __shfl_xor(cc, 8);
        cc += __shfl_xor(cc, 16);
        if (n == 0) lds[CC_OFF + ijl] = cc;
    }
#pragma unroll
    for (int k = 0; k < (BB * ND) / NTHR; ++k) {
        const int idx = tid + k * NTHR;
        lds[X_OFF + (idx & 31) * ROW_X + (idx >> 5)] = Xg[idx];
    }
    if (tid < TIJ) lds[LAM_OFF + tid] = Lam[ij0g + tid];

    const int lane = tid & 63;
    const int wave = tid >> 6;
    const int bql  = (lane >> 2) & 3;
    const int b0   = (wave * 4 + bql) * 4;   // 0..124 step 4

    __syncthreads();

    // ---- Phase A: lw[4b][8ij], streaming n (nq = interleaved quarter) ----
    {
        const int ijg = lane & 3;
        const int nq  = lane >> 4;           // 0..3
        const int ijA = ijg * 8;
        float lw[32];
#pragma unroll
        for (int k = 0; k < 32; ++k) lw[k] = 0.0f;
#pragma unroll
        for (int tt = 0; tt < 8; ++tt) {
            const int n = tt * 4 + nq;
            const float4 A0 = LD4(n * ROW_CAB + ijA);
            const float4 A1 = LD4(n * ROW_CAB + ijA + 4);
            const float4 C0 = LD4(n * ROW_CAB + 32 + ijA);
            const float4 C1 = LD4(n * ROW_CAB + 32 + ijA + 4);
            const float4 XV = LD4(X_OFF + n * ROW_X + b0);
            const float4 XS = make_float4(XV.x * XV.x, XV.y * XV.y,
                                          XV.z * XV.z, XV.w * XV.w);
#define PA_ONE(bi, XSc, XVc) \
            lw[bi*8+0] = fmaf(C0.x, XVc, fmaf(A0.x, XSc, lw[bi*8+0])); \
            lw[bi*8+1] = fmaf(C0.y, XVc, fmaf(A0.y, XSc, lw[bi*8+1])); \
            lw[bi*8+2] = fmaf(C0.z, XVc, fmaf(A0.z, XSc, lw[bi*8+2])); \
            lw[bi*8+3] = fmaf(C0.w, XVc, fmaf(A0.w, XSc, lw[bi*8+3])); \
            lw[bi*8+4] = fmaf(C1.x, XVc, fmaf(A1.x, XSc, lw[bi*8+4])); \
            lw[bi*8+5] = fmaf(C1.y, XVc, fmaf(A1.y, XSc, lw[bi*8+5])); \
            lw[bi*8+6] = fmaf(C1.z, XVc, fmaf(A1.z, XSc, lw[bi*8+6])); \
            lw[bi*8+7] = fmaf(C1.w, XVc, fmaf(A1.w, XSc, lw[bi*8+7]));
            PA_ONE(0, XS.x, XV.x)
            PA_ONE(1, XS.y, XV.y)
            PA_ONE(2, XS.z, XV.z)
            PA_ONE(3, XS.w, XV.w)
#undef PA_ONE
        }
        // combine the 4 nq-quarters (lane bits 4,5)
#pragma unroll
        for (int k = 0; k < 32; ++k) {
            lw[k] += __shfl_xor(lw[k], 16);
            lw[k] += __shfl_xor(lw[k], 32);
        }

        __syncthreads();   // all phase-A reads of cAB done before w overwrites R1

        // ---- Phase B: w = exp(clip(lw + Cc)) * Lam; write w[ij][b^swz] ----
        // lane handles bi = nq (b = b0 + nq); swizzle col by ijg at bits 4-5
        float lwb[8];
#pragma unroll
        for (int jj = 0; jj < 8; ++jj) {
            const float v0 = (nq & 2) ? lw[16 + jj] : lw[jj];
            const float v1 = (nq & 2) ? lw[24 + jj] : lw[8 + jj];
            lwb[jj] = (nq & 1) ? v1 : v0;
        }
        const int colw = (b0 + nq) ^ (ijg << 4);
#pragma unroll
        for (int jj = 0; jj < 8; ++jj) {
            const int ij = ijA + jj;
            float v = lwb[jj] + lds[CC_OFF + ij];
            v = fminf(fmaxf(v, -50.0f), 50.0f);
            lds[ij * ROW_W + colw] = __expf(v) * lds[LAM_OFF + ij];
        }
    }

    __syncthreads();

    // ---- Phase C: wk/wkv[4b][8n] accumulate over ij ----
    {
        const int ng  = lane & 3;
        const int n0  = ng * 8;
        const int ijq = lane >> 4;           // 0..3
        float wk[32], wkv[32], den4[4];
#pragma unroll
        for (int k = 0; k < 32; ++k) { wk[k] = 0.0f; wkv[k] = 0.0f; }
#pragma unroll
        for (int k = 0; k < 4; ++k) den4[k] = 0.0f;

#pragma unroll
        for (int tt = 0; tt < 8; ++tt) {
            const int ij = tt * 4 + ijq;     // 4 consecutive ij across ijq lanes
            const int colr = b0 ^ (((ij >> 3) & 3) << 4);   // matches phase-B swz
            const float4 WV = LD4(ij * ROW_W + colr);
            const float4 K0 = LD4(KKV_OFF + ij * ROW_KKV + n0);
            const float4 K1 = LD4(KKV_OFF + ij * ROW_KKV + n0 + 4);
            const float4 V0 = LD4(KKV_OFF + ij * ROW_KKV + 32 + n0);
            const float4 V1 = LD4(KKV_OFF + ij * ROW_KKV + 32 + n0 + 4);
#define PC_ONE(bi, WVc) \
            den4[bi] += WVc; \
            wk [bi*8+0] = fmaf(WVc, K0.x, wk [bi*8+0]); \
            wk [bi*8+1] = fmaf(WVc, K0.y, wk [bi*8+1]); \
            wk [bi*8+2] = fmaf(WVc, K0.z, wk [bi*8+2]); \
            wk [bi*8+3] = fmaf(WVc, K0.w, wk [bi*8+3]); \
            wk [bi*8+4] = fmaf(WVc, K1.x, wk [bi*8+4]); \
            wk [bi*8+5] = fmaf(WVc, K1.y, wk [bi*8+5]); \
            wk [bi*8+6] = fmaf(WVc, K1.z, wk [bi*8+6]); \
            wk [bi*8+7] = fmaf(WVc, K1.w, wk [bi*8+7]); \
            wkv[bi*8+0] = fmaf(WVc, V0.x, wkv[bi*8+0]); \
            wkv[bi*8+1] = fmaf(WVc, V0.y, wkv[bi*8+1]); \
            wkv[bi*8+2] = fmaf(WVc, V0.z, wkv[bi*8+2]); \
            wkv[bi*8+3] = fmaf(WVc, V0.w, wkv[bi*8+3]); \
            wkv[bi*8+4] = fmaf(WVc, V1.x, wkv[bi*8+4]); \
            wkv[bi*8+5] = fmaf(WVc, V1.y, wkv[bi*8+5]); \
            wkv[bi*8+6] = fmaf(WVc, V1.z, wkv[bi*8+6]); \
            wkv[bi*8+7] = fmaf(WVc, V1.w, wkv[bi*8+7]);
            PC_ONE(0, WV.x)
            PC_ONE(1, WV.y)
            PC_ONE(2, WV.z)
            PC_ONE(3, WV.w)
#undef PC_ONE
        }

        // combine over the 4 ijq groups (lane bits 4,5)
#pragma unroll
        for (int k = 0; k < 32; ++k) {
            wk[k]  += __shfl_xor(wk[k], 16);
            wk[k]  += __shfl_xor(wk[k], 32);
            wkv[k] += __shfl_xor(wkv[k], 16);
            wkv[k] += __shfl_xor(wkv[k], 32);
        }
#pragma unroll
        for (int k = 0; k < 4; ++k) {
            den4[k] += __shfl_xor(den4[k], 16);
            den4[k] += __shfl_xor(den4[k], 32);
        }

        __syncthreads();   // all phase-C w reads done; stage aliases region0

        // ---- Epilogue: num = X*wk + wkv -> LDS stage (packed, no holes) ----
        if (ijq == 0) {
            float num[32];
#pragma unroll
            for (int nj = 0; nj < 8; ++nj) {
                const float4 XQ = LD4(X_OFF + (n0 + nj) * ROW_X + b0);
                num[0 * 8 + nj] = fmaf(XQ.x, wk[0 * 8 + nj], wkv[0 * 8 + nj]);
                num[1 * 8 + nj] = fmaf(XQ.y, wk[1 * 8 + nj], wkv[1 * 8 + nj]);
                num[2 * 8 + nj] = fmaf(XQ.z, wk[2 * 8 + nj], wkv[2 * 8 + nj]);
                num[3 * 8 + nj] = fmaf(XQ.w, wk[3 * 8 + nj], wkv[3 * 8 + nj]);
            }
#pragma unroll
            for (int bi = 0; bi < 4; ++bi) {
                float* dst = &lds[(b0 + bi) * 32 + n0];
                *(float4*)dst =
                    make_float4(num[bi*8+0], num[bi*8+1], num[bi*8+2], num[bi*8+3]);
                *(float4*)(dst + 4) =
                    make_float4(num[bi*8+4], num[bi*8+5], num[bi*8+6], num[bi*8+7]);
            }
            if (ng == 0) {
#pragma unroll
                for (int bi = 0; bi < 4; ++bi)
                    lds[DEN_OFF + b0 + bi] = den4[bi];
            }
        }
    }

    __syncthreads();

    // ---- Coalesced block store: 4224 floats = 1056 float4, full lines ----
    float* __restrict__ dstg = part + (size_t)blk * PART_STRIDE;
    for (int k = tid; k < PART_STRIDE / 4; k += NTHR) {
        *(float4*)(dstg + 4 * k) = *(const float4*)&lds[4 * k];
    }
#undef LD4
}

// One block per b: sum partials over the 512 blocks (coalesced full-line
// reads: lane = j index within a block's num slice), divide, store out.
__global__ __launch_bounds__(512) void gmm_reduce(
    const float* __restrict__ part,
    float* __restrict__ out)
{
    const int b    = blockIdx.x;
    const int lane = threadIdx.x & 63;
    const int w    = threadIdx.x >> 6;       // 8 waves

    // lane<32: num[b][lane]; lane==32: den[b]; others idle
    const int off  = (lane < 32) ? (b * 32 + lane) : (DEN_OFF + b);
    const bool act = (lane <= 32);

    float a0 = 0.0f, a1 = 0.0f, a2 = 0.0f, a3 = 0.0f;
#pragma unroll
    for (int g = 0; g < 16; ++g) {
        const int blk = w + g * 32;
        if (act) {
            a0 += part[(size_t)(blk +  0) * PART_STRIDE + off];
            a1 += part[(size_t)(blk +  8) * PART_STRIDE + off];
            a2 += part[(size_t)(blk + 16) * PART_STRIDE + off];
            a3 += part[(size_t)(blk + 24) * PART_STRIDE + off];
        }
    }
    const float acc = (a0 + a1) + (a2 + a3);

    __shared__ float red[8][36];
    if (lane <= 32) red[w][lane] = acc;
    __syncthreads();

    if (threadIdx.x < 32) {
        float num = 0.0f, den = 0.0f;
#pragma unroll
        for (int k = 0; k < 8; ++k) {
            num += red[k][threadIdx.x];
            den += red[k][32];
        }
        out[b * 32 + threadIdx.x] = num / den;
    }
}

extern "C" void kernel_launch(void* const* d_in, const int* in_sizes, int n_in,
                              void* d_out, int out_size, void* d_ws, size_t ws_size,
                              hipStream_t stream)
{
    const float* X   = (const float*)d_in[0];
    const float* t   = (const float*)d_in[1];
    const float* Mu0 = (const float*)d_in[2];
    const float* Mu1 = (const float*)d_in[3];
    const float* S0  = (const float*)d_in[4];
    const float* S1  = (const float*)d_in[5];
    const float* Lam = (const float*)d_in[6];
    float* out  = (float*)d_out;
    float* part = (float*)d_ws;             // NBLK * PART_STRIDE floats (8.65 MB)

    gmm_fused<<<NBLK, NTHR, 0, stream>>>(X, t, Mu0, Mu1, S0, S1, Lam, part);
    gmm_reduce<<<BB, 512, 0, stream>>>(part, out);
}